// Round 5
// baseline (251.073 us; speedup 1.0000x reference)
//
#include <hip/hip_runtime.h>
#include <stdint.h>

#define IMPOSSIBLE -10000.0f
#define TT 4096
#define NN 64
#define BB 64
#define CHUNK 64            // time-steps per chunk
#define WARM 32             // warm-up steps (Birkhoff contraction ~0.34/step -> ~1e-14)
#define KCH (TT / CHUNK)    // 64 chunks per sequence

typedef _Float16 half2_t __attribute__((ext_vector_type(2)));

__device__ __forceinline__ float fdot2f(half2_t a, half2_t b, float c) {
#if __has_builtin(__builtin_amdgcn_fdot2)
  return __builtin_amdgcn_fdot2(a, b, c, false);
#else
  return c + (float)a[0] * (float)b[0] + (float)a[1] * (float)b[1];
#endif
}

// ---- bool-input dtype shim: harness may pass jnp.bool as int32 or uint8 ----
// mask[0][0..3] are always true (len >= T/2), so first word distinguishes:
//   uint8 layout -> 0x01010101 ; int32 layout -> 0x00000001
__device__ __forceinline__ bool bools_are_i32(const void* mask) {
  return ((const unsigned int*)mask)[0] == 1u;
}
__device__ __forceinline__ int bget(const void* p, int idx, bool i32) {
  return i32 ? ((const int*)p)[idx] : (int)((const unsigned char*)p)[idx];
}

// ---- DPP wave-64 reductions (VALU only, keeps DS pipe free) ----
__device__ __forceinline__ float wave_max_f32(float x) {
  int t;
#define STEP(ctrl)                                                            \
  t = __builtin_amdgcn_update_dpp(__float_as_int(x), __float_as_int(x), ctrl, \
                                  0xf, 0xf, false);                           \
  x = fmaxf(x, __int_as_float(t));
  STEP(0x111) STEP(0x112) STEP(0x114) STEP(0x118) STEP(0x142) STEP(0x143)
#undef STEP
  return __int_as_float(__builtin_amdgcn_readlane(__float_as_int(x), 63));
}

__device__ __forceinline__ float wave_sum_f32(float x) {
  int t;
#define STEP(ctrl)                                                         \
  t = __builtin_amdgcn_update_dpp(0, __float_as_int(x), ctrl, 0xf, 0xf,    \
                                  true);                                   \
  x += __int_as_float(t);
  STEP(0x111) STEP(0x112) STEP(0x114) STEP(0x118) STEP(0x142) STEP(0x143)
#undef STEP
  return __int_as_float(__builtin_amdgcn_readlane(__float_as_int(x), 63));
}

__device__ __forceinline__ int wave_sum_i32(int x) {
  int t;
#define STEP(ctrl)                                                      \
  t = __builtin_amdgcn_update_dpp(0, x, ctrl, 0xf, 0xf, true);          \
  x += t;
  STEP(0x111) STEP(0x112) STEP(0x114) STEP(0x118) STEP(0x142) STEP(0x143)
#undef STEP
  return __builtin_amdgcn_readlane(x, 63);
}

__device__ __forceinline__ float wave_lse(float x) {
  float m = wave_max_f32(x);
  float s = wave_sum_f32(__expf(x - m));
  return m + __logf(s);
}

__device__ __forceinline__ int bytesum4(unsigned int u) {
  return (int)((u * 0x01010101u) >> 24);  // bytes are 0/1, sum <= 4
}

// ---------------- z1: chunked forward recurrence with warm-up ----------------
// R4 body with ONE change: register headroom so the em prefetch ring is real.
//  * __launch_bounds__(64, 2): VGPR cap 256. R4's (64,4) clamped to 64 VGPR
//    and SPILLED (WRITE_SIZE 99KB -> 7233KB), which collapsed the prefetch
//    ring: the compiler could not keep the in-flight loads in registers, so
//    ~full global-load latency (~1900cy) landed on the serial chain each
//    step. Body needs ~90-110 VGPR: at <=128 all 4096 waves stay resident.
//  * ring deepened 4 -> 6 (covers load latency even if the step shrinks).
//  * no __syncthreads (single-wave block, DS in-order + lgkmcnt(0) only).
//  * 8x ds_read_b128 issued as one cluster into qa[8] (sched_barrier fences).
__global__ __launch_bounds__(64, 2) void crf_z1(
    const float* __restrict__ em, const void* __restrict__ mask,
    const float* __restrict__ trans, const float* __restrict__ startv,
    const float* __restrict__ endv, const void* __restrict__ ftr,
    const void* __restrict__ fst, const void* __restrict__ fen,
    float* __restrict__ out) {
  const int lane = threadIdx.x;
  const int b = blockIdx.x >> 6;   // KCH == 64
  const int c = blockIdx.x & 63;
  const bool i32 = bools_are_i32(mask);

  // len[b] = sum(mask[b, :])
  int ls = 0;
  if (i32) {
    const uint4* mv = (const uint4*)((const int*)mask + (size_t)b * TT);
#pragma unroll
    for (int k = 0; k < 16; ++k) {               // 1024 uint4 = 4096 ints
      uint4 w = mv[k * 64 + lane];
      ls += (int)(w.x + w.y + w.z + w.w);
    }
  } else {
    const uint4* mv = (const uint4*)((const unsigned char*)mask + (size_t)b * TT);
#pragma unroll
    for (int k = 0; k < 4; ++k) {                // 256 uint4 = 4096 bytes
      uint4 w = mv[k * 64 + lane];
      ls += bytesum4(w.x) + bytesum4(w.y) + bytesum4(w.z) + bytesum4(w.w);
    }
  }
  const int len = wave_sum_i32(ls);

  const int cL = c * CHUNK;
  if (cL >= len) return;  // chunk entirely beyond sequence end (wave-uniform)
  const int e_c = min(cL + CHUNK - 1, len - 1);
  const bool has_end = (len <= cL + CHUNK);  // len-1 inside this chunk

  // ET[i][j] = exp(masked trans[i][j]); lane j holds column j as 32 f16 pairs
  half2_t et2[32];
#pragma unroll
  for (int i2 = 0; i2 < 32; ++i2) {
    int i0 = 2 * i2, i1 = 2 * i2 + 1;
    float t0 = trans[i0 * NN + lane];
    float t1 = trans[i1 * NN + lane];
    if (bget(ftr, i0 * NN + lane, i32)) t0 = IMPOSSIBLE;
    if (bget(ftr, i1 * NN + lane, i32)) t1 = IMPOSSIBLE;
    half2_t h;
    h[0] = (_Float16)__expf(t0);
    h[1] = (_Float16)__expf(t1);
    et2[i2] = h;
  }

  const float* emb = em + (size_t)b * TT * NN + lane;
  float n, S = 0.f;
  int tb;
  if (c == 0) {
    float sv = startv[lane];
    if (bget(fst, lane, i32)) sv = IMPOSSIBLE;
    n = sv + emb[0];
    tb = 1;
  } else {
    int tw = cL - WARM;
    n = emb[(size_t)tw * NN];  // arbitrary init; warm-up forgets it
    tb = tw + 1;
  }

  __shared__ __align__(16) _Float16 pbuf[2][64];

  // depth-6 em prefetch ring: one load/iter, consumed 6 iters later; with
  // VGPR headroom the compiler keeps all 6 in flight (counted vmcnt, never
  // drained -- no barrier anywhere in the loop).
  float r0 = emb[(size_t)tb * NN];
  float r1 = emb[(size_t)min(tb + 1, TT - 1) * NN];
  float r2 = emb[(size_t)min(tb + 2, TT - 1) * NN];
  float r3 = emb[(size_t)min(tb + 3, TT - 1) * NN];
  float r4 = emb[(size_t)min(tb + 4, TT - 1) * NN];
  float r5 = emb[(size_t)min(tb + 5, TT - 1) * NN];

  for (int t = tb; t <= e_c; ++t) {
    float rn = emb[(size_t)min(t + 6, TT - 1) * NN];  // prefetch t+6
    float m = wave_max_f32(n);
    float p = __expf(n - m);
    const int par = t & 1;
    pbuf[par][lane] = (_Float16)p;
    // single wave: DS ops are in-order; lgkmcnt(0) makes the write visible to
    // the broadcast reads. No s_barrier, no vmcnt drain.
    asm volatile("s_waitcnt lgkmcnt(0)" ::: "memory");
    __builtin_amdgcn_sched_barrier(0);
    const uint4* pv = (const uint4*)pbuf[par];
    uint4 qa[8];
#pragma unroll
    for (int k = 0; k < 8; ++k) qa[k] = pv[k];  // 8x ds_read_b128, one cluster
    __builtin_amdgcn_sched_barrier(0);          // all reads issued before FMAs
    float s0 = 0.f, s1 = 0.f, s2 = 0.f, s3 = 0.f;
#pragma unroll
    for (int k = 0; k < 8; ++k) {
      s0 = fdot2f(__builtin_bit_cast(half2_t, qa[k].x), et2[4 * k + 0], s0);
      s1 = fdot2f(__builtin_bit_cast(half2_t, qa[k].y), et2[4 * k + 1], s1);
      s2 = fdot2f(__builtin_bit_cast(half2_t, qa[k].z), et2[4 * k + 2], s2);
      s3 = fdot2f(__builtin_bit_cast(half2_t, qa[k].w), et2[4 * k + 3], s3);
    }
    float s = (s0 + s1) + (s2 + s3);
    n = __logf(s) + r0;
    S += m;
    r0 = r1; r1 = r2; r2 = r3; r3 = r4; r4 = r5; r5 = rn;
    if (c > 0 && t == cL - 1) S = -wave_lse(n);  // discard warm-up scale
  }

  float ev = endv[lane];
  if (bget(fen, lane, i32)) ev = IMPOSSIBLE;
  float zc = has_end ? wave_lse(n + ev) : wave_lse(n);
  if (lane == 0) atomicAdd(out + b, S + zc);
}

// ---------------- z0: gold-path score, wave-per-row ballot version ----------
// (unchanged: ~12 us under the overhead model)
__global__ __launch_bounds__(256) void crf_z0(
    const float* __restrict__ em, const void* __restrict__ mask,
    const void* __restrict__ target, const float* __restrict__ trans,
    const float* __restrict__ startv, const float* __restrict__ endv,
    const void* __restrict__ ftr, const void* __restrict__ fst,
    const void* __restrict__ fen, float* __restrict__ out) {
  const int tid = threadIdx.x;
  const int lane = tid & 63;
  const int w = tid >> 6;
  const int b = blockIdx.x >> 4;
  const int q = blockIdx.x & 15;
  const bool i32 = bools_are_i32(mask);

  __shared__ int lred[4];
  __shared__ int tags[257];
  __shared__ float fred4[4];

  // ---- block-wide len[b] = sum(mask[b,:]) ----
  int ls = 0;
  if (i32) {
    const uint4* mv = (const uint4*)((const int*)mask + (size_t)b * TT);
#pragma unroll
    for (int k = 0; k < 4; ++k) {   // 1024 uint4 = 4096 ints
      uint4 u = mv[k * 256 + tid];
      ls += (int)(u.x + u.y + u.z + u.w);
    }
  } else {
    uint4 u = ((const uint4*)((const unsigned char*)mask + (size_t)b * TT))[tid];
    ls = bytesum4(u.x) + bytesum4(u.y) + bytesum4(u.z) + bytesum4(u.w);
  }
  ls = wave_sum_i32(ls);
  if (lane == 0) lred[w] = ls;

  // ---- tag extraction: wave w scans rows t0 + w*64 .. +63 ----
  const int t0 = q * 256;
  int mytag = 0;
  const size_t rb = ((size_t)b * TT + t0 + (size_t)w * 64) * NN + lane;
  if (i32) {
    const int* tg = (const int*)target + rb;
    for (int k = 0; k < 8; ++k) {
      int v[8];
#pragma unroll
      for (int j = 0; j < 8; ++j) v[j] = tg[(size_t)(k * 8 + j) * NN];
#pragma unroll
      for (int j = 0; j < 8; ++j) {
        unsigned long long bm = __ballot(v[j] != 0);
        int tv = __ffsll(bm) - 1;
        if (lane == k * 8 + j) mytag = tv;
      }
    }
  } else {
    const unsigned char* tg = (const unsigned char*)target + rb;
    for (int k = 0; k < 8; ++k) {
      int v[8];
#pragma unroll
      for (int j = 0; j < 8; ++j) v[j] = (int)tg[(size_t)(k * 8 + j) * NN];
#pragma unroll
      for (int j = 0; j < 8; ++j) {
        unsigned long long bm = __ballot(v[j] != 0);
        int tv = __ffsll(bm) - 1;
        if (lane == k * 8 + j) mytag = tv;
      }
    }
  }
  tags[tid + 1] = mytag;
  if (w == 0) {  // boundary row t0-1 for the block's first transition
    int rp = (t0 == 0) ? 0 : t0 - 1;
    int vv = i32 ? ((const int*)target)[((size_t)b * TT + rp) * NN + lane]
                 : (int)((const unsigned char*)
                       target)[((size_t)b * TT + rp) * NN + lane];
    unsigned long long bm = __ballot(vv != 0);
    int tv = __ffsll(bm) - 1;
    if (tid == 0) tags[0] = (t0 == 0) ? 0 : tv;
  }
  __syncthreads();  // publish lred + tags
  const int len = lred[0] + lred[1] + lred[2] + lred[3];

  const int t = t0 + tid;
  float contrib = 0.f;
  if (t < len) {
    int tg = tags[tid + 1];
    float emv = em[((size_t)b * TT + t) * NN + tg];
    if (t == 0) {
      float sv = startv[tg];
      if (bget(fst, tg, i32)) sv = IMPOSSIBLE;
      contrib = sv + emv;
    } else {
      int tp = tags[tid];
      float tv = trans[tp * NN + tg];
      if (bget(ftr, tp * NN + tg, i32)) tv = IMPOSSIBLE;
      contrib = tv + emv;
    }
    if (t == len - 1) {
      float evv = endv[tg];
      if (bget(fen, tg, i32)) evv = IMPOSSIBLE;
      contrib += evv;
    }
  }
  float wsum = wave_sum_f32(contrib);
  if (lane == 0) fred4[w] = wsum;
  __syncthreads();
  if (tid == 0)
    atomicAdd(out + b, -(fred4[0] + fred4[1] + fred4[2] + fred4[3]));
}

extern "C" void kernel_launch(void* const* d_in, const int* in_sizes, int n_in,
                              void* d_out, int out_size, void* d_ws,
                              size_t ws_size, hipStream_t stream) {
  const float* em = (const float*)d_in[0];
  const void* mask = d_in[1];
  const void* target = d_in[2];
  const float* trans = (const float*)d_in[3];
  const float* startv = (const float*)d_in[4];
  const float* endv = (const float*)d_in[5];
  const void* ftr = d_in[6];
  const void* fst = d_in[7];
  const void* fen = d_in[8];
  float* out = (float*)d_out;

  hipMemsetAsync(out, 0, BB * sizeof(float), stream);
  crf_z1<<<dim3(BB * KCH), dim3(64), 0, stream>>>(em, mask, trans, startv,
                                                  endv, ftr, fst, fen, out);
  crf_z0<<<dim3(BB * 16), dim3(256), 0, stream>>>(
      em, mask, target, trans, startv, endv, ftr, fst, fen, out);
}

// Round 6
// 227.718 us; speedup vs baseline: 1.1026x; 1.1026x over previous
//
#include <hip/hip_runtime.h>
#include <stdint.h>

#define IMPOSSIBLE -10000.0f
#define TT 4096
#define NN 64
#define BB 64
#define CHUNK 128           // time-steps per chunk (discriminating experiment: was 64)
#define WARM 32             // warm-up steps (Birkhoff contraction ~0.34/step -> ~1e-14)
#define KCH (TT / CHUNK)    // 32 chunks per sequence

typedef _Float16 half2_t __attribute__((ext_vector_type(2)));

__device__ __forceinline__ float fdot2f(half2_t a, half2_t b, float c) {
#if __has_builtin(__builtin_amdgcn_fdot2)
  return __builtin_amdgcn_fdot2(a, b, c, false);
#else
  return c + (float)a[0] * (float)b[0] + (float)a[1] * (float)b[1];
#endif
}

// ---- bool-input dtype shim: harness may pass jnp.bool as int32 or uint8 ----
// mask[0][0..3] are always true (len >= T/2), so first word distinguishes:
//   uint8 layout -> 0x01010101 ; int32 layout -> 0x00000001
__device__ __forceinline__ bool bools_are_i32(const void* mask) {
  return ((const unsigned int*)mask)[0] == 1u;
}
__device__ __forceinline__ int bget(const void* p, int idx, bool i32) {
  return i32 ? ((const int*)p)[idx] : (int)((const unsigned char*)p)[idx];
}

// ---- DPP wave-64 reductions (VALU only, keeps DS pipe free) ----
__device__ __forceinline__ float wave_max_f32(float x) {
  int t;
#define STEP(ctrl)                                                            \
  t = __builtin_amdgcn_update_dpp(__float_as_int(x), __float_as_int(x), ctrl, \
                                  0xf, 0xf, false);                           \
  x = fmaxf(x, __int_as_float(t));
  STEP(0x111) STEP(0x112) STEP(0x114) STEP(0x118) STEP(0x142) STEP(0x143)
#undef STEP
  return __int_as_float(__builtin_amdgcn_readlane(__float_as_int(x), 63));
}

__device__ __forceinline__ float wave_sum_f32(float x) {
  int t;
#define STEP(ctrl)                                                         \
  t = __builtin_amdgcn_update_dpp(0, __float_as_int(x), ctrl, 0xf, 0xf,    \
                                  true);                                   \
  x += __int_as_float(t);
  STEP(0x111) STEP(0x112) STEP(0x114) STEP(0x118) STEP(0x142) STEP(0x143)
#undef STEP
  return __int_as_float(__builtin_amdgcn_readlane(__float_as_int(x), 63));
}

__device__ __forceinline__ int wave_sum_i32(int x) {
  int t;
#define STEP(ctrl)                                                      \
  t = __builtin_amdgcn_update_dpp(0, x, ctrl, 0xf, 0xf, true);          \
  x += t;
  STEP(0x111) STEP(0x112) STEP(0x114) STEP(0x118) STEP(0x142) STEP(0x143)
#undef STEP
  return __builtin_amdgcn_readlane(x, 63);
}

__device__ __forceinline__ float wave_lse(float x) {
  float m = wave_max_f32(x);
  float s = wave_sum_f32(__expf(x - m));
  return m + __logf(s);
}

__device__ __forceinline__ int bytesum4(unsigned int u) {
  return (int)((u * 0x01010101u) >> 24);  // bytes are 0/1, sum <= 4
}

// ---------------- z1: chunked forward recurrence with warm-up ----------------
// DISCRIMINATING EXPERIMENT (round 6): CHUNK 64 -> 128, everything else held
// at the verified R5 configuration (spill-free, barrier-free, clustered reads).
//   DS-contention theory: 8 waves/CU instead of 16 halves the per-CU DS-pipe
//     queue (9 DS instrs x waves x ~11cy per step-period) -> z1 ~50-70us.
//   Chain-latency theory: per-step cost unchanged -> 159 steps -> ~165us.
// The sign of the result selects the theory for round 7.
__global__ __launch_bounds__(64, 2) void crf_z1(
    const float* __restrict__ em, const void* __restrict__ mask,
    const float* __restrict__ trans, const float* __restrict__ startv,
    const float* __restrict__ endv, const void* __restrict__ ftr,
    const void* __restrict__ fst, const void* __restrict__ fen,
    float* __restrict__ out) {
  const int lane = threadIdx.x;
  const int b = blockIdx.x >> 5;   // KCH == 32
  const int c = blockIdx.x & 31;
  const bool i32 = bools_are_i32(mask);

  // len[b] = sum(mask[b, :])
  int ls = 0;
  if (i32) {
    const uint4* mv = (const uint4*)((const int*)mask + (size_t)b * TT);
#pragma unroll
    for (int k = 0; k < 16; ++k) {               // 1024 uint4 = 4096 ints
      uint4 w = mv[k * 64 + lane];
      ls += (int)(w.x + w.y + w.z + w.w);
    }
  } else {
    const uint4* mv = (const uint4*)((const unsigned char*)mask + (size_t)b * TT);
#pragma unroll
    for (int k = 0; k < 4; ++k) {                // 256 uint4 = 4096 bytes
      uint4 w = mv[k * 64 + lane];
      ls += bytesum4(w.x) + bytesum4(w.y) + bytesum4(w.z) + bytesum4(w.w);
    }
  }
  const int len = wave_sum_i32(ls);

  const int cL = c * CHUNK;
  if (cL >= len) return;  // chunk entirely beyond sequence end (wave-uniform)
  const int e_c = min(cL + CHUNK - 1, len - 1);
  const bool has_end = (len <= cL + CHUNK);  // len-1 inside this chunk

  // ET[i][j] = exp(masked trans[i][j]); lane j holds column j as 32 f16 pairs
  half2_t et2[32];
#pragma unroll
  for (int i2 = 0; i2 < 32; ++i2) {
    int i0 = 2 * i2, i1 = 2 * i2 + 1;
    float t0 = trans[i0 * NN + lane];
    float t1 = trans[i1 * NN + lane];
    if (bget(ftr, i0 * NN + lane, i32)) t0 = IMPOSSIBLE;
    if (bget(ftr, i1 * NN + lane, i32)) t1 = IMPOSSIBLE;
    half2_t h;
    h[0] = (_Float16)__expf(t0);
    h[1] = (_Float16)__expf(t1);
    et2[i2] = h;
  }

  const float* emb = em + (size_t)b * TT * NN + lane;
  float n, S = 0.f;
  int tb;
  if (c == 0) {
    float sv = startv[lane];
    if (bget(fst, lane, i32)) sv = IMPOSSIBLE;
    n = sv + emb[0];
    tb = 1;
  } else {
    int tw = cL - WARM;        // WARM(32) < CHUNK(128): warm-up window exists
    n = emb[(size_t)tw * NN];  // arbitrary init; warm-up forgets it
    tb = tw + 1;
  }

  __shared__ __align__(16) _Float16 pbuf[2][64];

  // depth-6 em prefetch ring: one load/iter, consumed 6 iters later; vmcnt
  // never drains in the loop (no barrier anywhere).
  float r0 = emb[(size_t)tb * NN];
  float r1 = emb[(size_t)min(tb + 1, TT - 1) * NN];
  float r2 = emb[(size_t)min(tb + 2, TT - 1) * NN];
  float r3 = emb[(size_t)min(tb + 3, TT - 1) * NN];
  float r4 = emb[(size_t)min(tb + 4, TT - 1) * NN];
  float r5 = emb[(size_t)min(tb + 5, TT - 1) * NN];

  for (int t = tb; t <= e_c; ++t) {
    float rn = emb[(size_t)min(t + 6, TT - 1) * NN];  // prefetch t+6
    float m = wave_max_f32(n);
    float p = __expf(n - m);
    const int par = t & 1;
    pbuf[par][lane] = (_Float16)p;
    // single wave: DS ops are in-order; lgkmcnt(0) makes the write visible to
    // the broadcast reads. No s_barrier, no vmcnt drain.
    asm volatile("s_waitcnt lgkmcnt(0)" ::: "memory");
    __builtin_amdgcn_sched_barrier(0);
    const uint4* pv = (const uint4*)pbuf[par];
    uint4 qa[8];
#pragma unroll
    for (int k = 0; k < 8; ++k) qa[k] = pv[k];  // 8x ds_read_b128, one cluster
    __builtin_amdgcn_sched_barrier(0);          // all reads issued before FMAs
    float s0 = 0.f, s1 = 0.f, s2 = 0.f, s3 = 0.f;
#pragma unroll
    for (int k = 0; k < 8; ++k) {
      s0 = fdot2f(__builtin_bit_cast(half2_t, qa[k].x), et2[4 * k + 0], s0);
      s1 = fdot2f(__builtin_bit_cast(half2_t, qa[k].y), et2[4 * k + 1], s1);
      s2 = fdot2f(__builtin_bit_cast(half2_t, qa[k].z), et2[4 * k + 2], s2);
      s3 = fdot2f(__builtin_bit_cast(half2_t, qa[k].w), et2[4 * k + 3], s3);
    }
    float s = (s0 + s1) + (s2 + s3);
    n = __logf(s) + r0;
    S += m;
    r0 = r1; r1 = r2; r2 = r3; r3 = r4; r4 = r5; r5 = rn;
    if (c > 0 && t == cL - 1) S = -wave_lse(n);  // discard warm-up scale
  }

  float ev = endv[lane];
  if (bget(fen, lane, i32)) ev = IMPOSSIBLE;
  float zc = has_end ? wave_lse(n + ev) : wave_lse(n);
  if (lane == 0) atomicAdd(out + b, S + zc);
}

// ---------------- z0: gold-path score, wave-per-row ballot version ----------
// (unchanged: ~12 us under the overhead model)
__global__ __launch_bounds__(256) void crf_z0(
    const float* __restrict__ em, const void* __restrict__ mask,
    const void* __restrict__ target, const float* __restrict__ trans,
    const float* __restrict__ startv, const float* __restrict__ endv,
    const void* __restrict__ ftr, const void* __restrict__ fst,
    const void* __restrict__ fen, float* __restrict__ out) {
  const int tid = threadIdx.x;
  const int lane = tid & 63;
  const int w = tid >> 6;
  const int b = blockIdx.x >> 4;
  const int q = blockIdx.x & 15;
  const bool i32 = bools_are_i32(mask);

  __shared__ int lred[4];
  __shared__ int tags[257];
  __shared__ float fred4[4];

  // ---- block-wide len[b] = sum(mask[b,:]) ----
  int ls = 0;
  if (i32) {
    const uint4* mv = (const uint4*)((const int*)mask + (size_t)b * TT);
#pragma unroll
    for (int k = 0; k < 4; ++k) {   // 1024 uint4 = 4096 ints
      uint4 u = mv[k * 256 + tid];
      ls += (int)(u.x + u.y + u.z + u.w);
    }
  } else {
    uint4 u = ((const uint4*)((const unsigned char*)mask + (size_t)b * TT))[tid];
    ls = bytesum4(u.x) + bytesum4(u.y) + bytesum4(u.z) + bytesum4(u.w);
  }
  ls = wave_sum_i32(ls);
  if (lane == 0) lred[w] = ls;

  // ---- tag extraction: wave w scans rows t0 + w*64 .. +63 ----
  const int t0 = q * 256;
  int mytag = 0;
  const size_t rb = ((size_t)b * TT + t0 + (size_t)w * 64) * NN + lane;
  if (i32) {
    const int* tg = (const int*)target + rb;
    for (int k = 0; k < 8; ++k) {
      int v[8];
#pragma unroll
      for (int j = 0; j < 8; ++j) v[j] = tg[(size_t)(k * 8 + j) * NN];
#pragma unroll
      for (int j = 0; j < 8; ++j) {
        unsigned long long bm = __ballot(v[j] != 0);
        int tv = __ffsll(bm) - 1;
        if (lane == k * 8 + j) mytag = tv;
      }
    }
  } else {
    const unsigned char* tg = (const unsigned char*)target + rb;
    for (int k = 0; k < 8; ++k) {
      int v[8];
#pragma unroll
      for (int j = 0; j < 8; ++j) v[j] = (int)tg[(size_t)(k * 8 + j) * NN];
#pragma unroll
      for (int j = 0; j < 8; ++j) {
        unsigned long long bm = __ballot(v[j] != 0);
        int tv = __ffsll(bm) - 1;
        if (lane == k * 8 + j) mytag = tv;
      }
    }
  }
  tags[tid + 1] = mytag;
  if (w == 0) {  // boundary row t0-1 for the block's first transition
    int rp = (t0 == 0) ? 0 : t0 - 1;
    int vv = i32 ? ((const int*)target)[((size_t)b * TT + rp) * NN + lane]
                 : (int)((const unsigned char*)
                       target)[((size_t)b * TT + rp) * NN + lane];
    unsigned long long bm = __ballot(vv != 0);
    int tv = __ffsll(bm) - 1;
    if (tid == 0) tags[0] = (t0 == 0) ? 0 : tv;
  }
  __syncthreads();  // publish lred + tags
  const int len = lred[0] + lred[1] + lred[2] + lred[3];

  const int t = t0 + tid;
  float contrib = 0.f;
  if (t < len) {
    int tg = tags[tid + 1];
    float emv = em[((size_t)b * TT + t) * NN + tg];
    if (t == 0) {
      float sv = startv[tg];
      if (bget(fst, tg, i32)) sv = IMPOSSIBLE;
      contrib = sv + emv;
    } else {
      int tp = tags[tid];
      float tv = trans[tp * NN + tg];
      if (bget(ftr, tp * NN + tg, i32)) tv = IMPOSSIBLE;
      contrib = tv + emv;
    }
    if (t == len - 1) {
      float evv = endv[tg];
      if (bget(fen, tg, i32)) evv = IMPOSSIBLE;
      contrib += evv;
    }
  }
  float wsum = wave_sum_f32(contrib);
  if (lane == 0) fred4[w] = wsum;
  __syncthreads();
  if (tid == 0)
    atomicAdd(out + b, -(fred4[0] + fred4[1] + fred4[2] + fred4[3]));
}

extern "C" void kernel_launch(void* const* d_in, const int* in_sizes, int n_in,
                              void* d_out, int out_size, void* d_ws,
                              size_t ws_size, hipStream_t stream) {
  const float* em = (const float*)d_in[0];
  const void* mask = d_in[1];
  const void* target = d_in[2];
  const float* trans = (const float*)d_in[3];
  const float* startv = (const float*)d_in[4];
  const float* endv = (const float*)d_in[5];
  const void* ftr = d_in[6];
  const void* fst = d_in[7];
  const void* fen = d_in[8];
  float* out = (float*)d_out;

  hipMemsetAsync(out, 0, BB * sizeof(float), stream);
  crf_z1<<<dim3(BB * KCH), dim3(64), 0, stream>>>(em, mask, trans, startv,
                                                  endv, ftr, fst, fen, out);
  crf_z0<<<dim3(BB * 16), dim3(256), 0, stream>>>(
      em, mask, target, trans, startv, endv, ftr, fst, fen, out);
}